// Round 13
// baseline (206.356 us; speedup 1.0000x reference)
//
#include <hip/hip_runtime.h>
#include <math.h>

#define NB 1024
#define NF 36
#define ED 256
#define NK 8
#define NN2 1296   // 36*36

typedef _Float16 f16;
typedef f16 f16x4 __attribute__((ext_vector_type(4)));
typedef f16 f16x8 __attribute__((ext_vector_type(8)));
typedef float f32x4 __attribute__((ext_vector_type(4)));

#define WXSTR 136     // f16 per Wx half-row (128 + 8 pad)
#define WXHSZ 13056   // 48 * WXSTR * 2 bytes
#define NFRAG 1536    // 3 row-tiles * 8 kc * 64 lanes, f16x8 each

// ---- ntn_main LDS: Xh | Wxh(/Pp/Ts) | v1 v2 Uw L = 39540 B -> 4 blocks/CU ----
#define XH_OFF  0
#define WXH_OFF 24576
#define V_OFF   (24576 + WXHSZ)                  // 37632
#define SMEM_MAIN (V_OFF + (72 + 72 + 9 + 324) * 4)   // 39540; 4x <= 163840

// ---- wpack LDS: [16][264] f16 tile ----
#define SMEM_PREP 8448

#define TWO_LOG2E 2.8853900817779268f
#define C1F (0.0625f * TWO_LOG2E)

__device__ __forceinline__ f32x4 mfma16(f16x8 a, f16x8 b, f32x4 c) {
    return __builtin_amdgcn_mfma_f32_16x16x32_f16(a, b, c, 0, 0, 0);
}

// W fragment pack only: one (k,ct) tile per block, 128 blocks.
__global__ __launch_bounds__(256, 4) void wpack(
    const float* __restrict__ W, f16x8* __restrict__ WfH)
{
    extern __shared__ char psmem[];
    const int blk = blockIdx.x;
    const int t = threadIdx.x;
    const int k = blk >> 4, ct = blk & 15;
    f16* Wl = (f16*)psmem;                    // [16][264] f16, scaled x16
    {
        const int r = t >> 4, seg = t & 15;
        const float* src = W + ((size_t)(k * 256 + ct * 16 + r)) * 256 + seg * 16;
        f16* d = Wl + r * 264 + seg * 16;
        #pragma unroll
        for (int j4 = 0; j4 < 4; ++j4) {
            float4 a = ((const float4*)src)[j4];
            d[j4 * 4 + 0] = (f16)(a.x * 16.0f);
            d[j4 * 4 + 1] = (f16)(a.y * 16.0f);
            d[j4 * 4 + 2] = (f16)(a.z * 16.0f);
            d[j4 * 4 + 3] = (f16)(a.w * 16.0f);
        }
    }
    __syncthreads();
    f16x8* dst = WfH + (size_t)(k * 16 + ct) * 8 * 64;
    #pragma unroll
    for (int e0 = 0; e0 < 2; ++e0) {
        const int e = t + e0 * 256;
        const int kc = e >> 6, el = e & 63, qd = el >> 4, l15 = el & 15;
        dst[e] = *(const f16x8*)(Wl + l15 * 264 + (kc * 4 + qd) * 8);
    }
}

// P1 step: one kc of Wx^T = W*X (swapped operands) for ONE k, 6 MFMA.
#define P1_STEP(ACC, WKP, H, KC) do {                                         \
    f16x8 w0_ = (WKP)[((((H) * 8 + wave) * 8) + (KC)) * 64 + lane];           \
    f16x8 w1_ = (WKP)[((((H) * 8 + wave + 4) * 8) + (KC)) * 64 + lane];       \
    _Pragma("unroll")                                                         \
    for (int rt_ = 0; rt_ < 3; ++rt_) {                                       \
        f16x8 ah_ = Xh[(rt_ * 8 + (KC)) * 64 + lane];                         \
        ACC[rt_][0] = mfma16(w0_, ah_, ACC[rt_][0]);                          \
        ACC[rt_][1] = mfma16(w1_, ah_, ACC[rt_][1]);                          \
    }                                                                         \
} while (0)

#define P2_TILE(IT, H, KK) do {                                               \
    const int p_ = wave + (IT) * 4;                                           \
    if (p_ < 9) {                                                             \
        const int nt_ = p_ / 3, mt_ = p_ % 3;                                 \
        const f16* wp_ = Wxh + (nt_ * 16 + l15) * WXSTR + quad * 8;           \
        _Pragma("unroll")                                                     \
        for (int kc2_ = 0; kc2_ < 4; ++kc2_) {                                \
            f16x8 pah_ = *(const f16x8*)(wp_ + kc2_ * 32);                    \
            f16x8 pbh_ = Xh[(mt_ * 8 + (H) * 4 + kc2_) * 64 + lane];          \
            sacc[KK][IT] = mfma16(pah_, pbh_, sacc[KK][IT]);                  \
        }                                                                     \
    }                                                                         \
} while (0)

#define ZERO_ACC(ACC) do {                                                    \
    _Pragma("unroll")                                                         \
    for (int i_ = 0; i_ < 3; ++i_) {                                          \
        ACC[i_][0] = (f32x4){0.f, 0.f, 0.f, 0.f};                             \
        ACC[i_][1] = (f32x4){0.f, 0.f, 0.f, 0.f};                             \
    }                                                                         \
} while (0)

#define STORE_WX(ACC) do {                                                    \
    _Pragma("unroll")                                                         \
    for (int rt_ = 0; rt_ < 3; ++rt_) {                                       \
        const int n_ = rt_ * 16 + l15;                                        \
        _Pragma("unroll")                                                     \
        for (int j2_ = 0; j2_ < 2; ++j2_) {                                   \
            const int cb_ = (j2_ ? (wave + 4) : wave) * 16 + quad * 4;        \
            f16x4 h4_;                                                        \
            _Pragma("unroll")                                                 \
            for (int r_ = 0; r_ < 4; ++r_) h4_[r_] = (f16)(ACC[rt_][j2_][r_]);\
            *(f16x4*)(Wxh + n_ * WXSTR + cb_) = h4_;                          \
        }                                                                     \
    }                                                                         \
} while (0)

#define SEG_FUSED(ACC, WKP, H1, HP, KKP) do {                                 \
    _Pragma("unroll")                                                         \
    for (int kc_ = 0; kc_ < 8; ++kc_) {                                       \
        P1_STEP(ACC, WKP, H1, kc_);                                           \
        if (kc_ == 1) P2_TILE(0, HP, KKP);                                    \
        if (kc_ == 3) P2_TILE(1, HP, KKP);                                    \
        if (kc_ == 5) P2_TILE(2, HP, KKP);                                    \
    }                                                                         \
} while (0)

// Fused main: raw-texts staging (X fragments built in-block; no XfH buffer),
// in-block v12 (per-wave register V-frags, 18 MFMA, Pp through the Wxh LDS
// region, one reduce -> v1s2/v2s2), then the R10 pipeline verbatim.
__global__ __launch_bounds__(256, 4) void ntn_main(
    const float* __restrict__ texts,
    const f16x8* __restrict__ WfH,
    const float* __restrict__ V1w, const float* __restrict__ V1b,
    const float* __restrict__ V2w, const float* __restrict__ V2b,
    const float* __restrict__ Wb,
    const float* __restrict__ Uw, const float* __restrict__ Ubp,
    float* __restrict__ out)
{
    extern __shared__ char smem[];
    f16x8* Xh   = (f16x8*)(smem + XH_OFF);
    f16*   Wxh  = (f16*)(smem + WXH_OFF);
    float* v1s2 = (float*)(smem + V_OFF);      // [2][36], pre-scaled by 2*log2e
    float* v2s2 = v1s2 + 72;                   // [2][36]
    float* Uws  = v1s2 + 144;                  // [9]
    float* Ls   = v1s2 + 153;                  // [324] logits

    const int id  = blockIdx.x;
    const int xcd = id & 7;
    const int rem = id >> 3;
    const int kp  = rem & 3;
    const int b   = ((rem >> 2) << 3) | xcd;
    const int k0  = kp * 2;

    const int t    = threadIdx.x;
    const int wave = t >> 6;
    const int lane = t & 63;
    const int quad = lane >> 4;
    const int l15  = lane & 15;

    // ---- stage: raw texts -> hi/lo fragments (regs) + Xh LDS ----
    const float* xb = texts + (size_t)b * NF * ED;
    f16x8 FH[6], FL[6];
    #pragma unroll
    for (int i0 = 0; i0 < 6; ++i0) {
        const int i = t + i0 * 256;            // frag f = i0*4 + wave
        const int rt = i >> 9, kc = (i >> 6) & 7;
        const int row = rt * 16 + l15;
        f16x8 hi, lo;
        if (row < NF) {
            const float* s = xb + row * ED + kc * 32 + quad * 8;
            float4 a = *(const float4*)s;
            float4 c = *(const float4*)(s + 4);
            float v[8] = {a.x, a.y, a.z, a.w, c.x, c.y, c.z, c.w};
            #pragma unroll
            for (int j = 0; j < 8; ++j) {
                f16 h = (f16)v[j];
                hi[j] = h;
                lo[j] = (f16)(v[j] - (float)h);
            }
        } else {
            #pragma unroll
            for (int j = 0; j < 8; ++j) { hi[j] = (f16)0.f; lo[j] = (f16)0.f; }
        }
        FH[i0] = hi;
        FL[i0] = lo;
        Xh[i] = hi;
    }
    // ---- per-wave V fragments (kc = wave, wave+4) in registers ----
    f16x8 VH[2], VL[2];
    #pragma unroll
    for (int s = 0; s < 2; ++s) {
        const int kcv = wave + 4 * s;
        const int which = l15 >> 3, kk = l15 & 7;
        const float* src  = (which ? V2w : V1w) + kk * 256 + kcv * 32 + quad * 8;
        const float* srcb = Wb + kk * 256 + kcv * 32 + quad * 8;
        #pragma unroll
        for (int j = 0; j < 8; ++j) {
            float sv = src[j] + (which ? srcb[j] : 0.f);
            sv *= 16.0f;
            f16 h = (f16)sv;
            VH[s][j] = h;
            VL[s][j] = (f16)(sv - (float)h);
        }
    }
    // ---- v12 partials (18 MFMA) -> Pp (overlays Wxh region) ----
    {
        f32x4 pacc[3];
        #pragma unroll
        for (int rt = 0; rt < 3; ++rt) pacc[rt] = (f32x4){0.f, 0.f, 0.f, 0.f};
        #pragma unroll
        for (int rt = 0; rt < 3; ++rt)
            #pragma unroll
            for (int s = 0; s < 2; ++s) {
                const int i0 = rt * 2 + s;     // frag (rt, kc = wave + 4*s)
                pacc[rt] = mfma16(FH[i0], VH[s], pacc[rt]);
                pacc[rt] = mfma16(FH[i0], VL[s], pacc[rt]);
                pacc[rt] = mfma16(FL[i0], VH[s], pacc[rt]);
            }
        f32x4* Pp = (f32x4*)Wxh;               // 12 x 64 x 16B = 12288 <= 13056
        #pragma unroll
        for (int rt = 0; rt < 3; ++rt)
            Pp[(wave * 3 + rt) * 64 + lane] = pacc[rt];
    }
    if (t < 8) Uws[t] = Uw[t];
    if (t == 8) Uws[8] = Ubp[0];
    __syncthreads();   // (0) Xh + Pp visible

    // ---- reduce v12 partials; keep only this block's 2 k's ----
    if (wave < 3) {
        const f32x4* Pp = (const f32x4*)Wxh;
        f32x4 racc = Pp[(0 * 3 + wave) * 64 + lane];
        #pragma unroll
        for (int w = 1; w < 4; ++w) racc += Pp[(w * 3 + wave) * 64 + lane];
        const int which = l15 >> 3, kk = l15 & 7;
        if (kk == k0 || kk == k0 + 1) {
            const int kidx = kk - k0;
            const float bias = which ? V2b[kk] : V1b[kk];
            #pragma unroll
            for (int r = 0; r < 4; ++r) {
                const int n = wave * 16 + quad * 4 + r;
                if (n < NF)
                    (which ? v2s2 : v1s2)[kidx * 36 + n] =
                        (racc[r] * 0.0625f + bias) * TWO_LOG2E;
            }
        }
    }

    const f16x8* Wk0 = WfH + (size_t)k0 * 8192;
    const f16x8* Wk1 = Wk0 + 8192;

    f32x4 sacc[2][3];
    #pragma unroll
    for (int kk = 0; kk < 2; ++kk)
        #pragma unroll
        for (int it = 0; it < 3; ++it) sacc[kk][it] = (f32x4){0.f, 0.f, 0.f, 0.f};

    f32x4 acc[3][2];

    // ===== seg 0: P1(h0,k0) =====
    ZERO_ACC(acc);
    #pragma unroll
    for (int kc = 0; kc < 8; ++kc) P1_STEP(acc, Wk0, 0, kc);
    __syncthreads();             // (1) Pp reads done before Wxh store
    STORE_WX(acc);
    __syncthreads();             // (2) Wx(h0,k0) visible

    // ===== seg 1: P2(h0,k0) || P1(h0,k1) =====
    ZERO_ACC(acc);
    SEG_FUSED(acc, Wk1, 0, 0, 0);
    __syncthreads();             // (3)
    STORE_WX(acc);
    __syncthreads();             // (4) Wx(h0,k1) visible

    // ===== seg 2: P2(h0,k1) || P1(h1,k0) =====
    ZERO_ACC(acc);
    SEG_FUSED(acc, Wk0, 1, 0, 1);
    __syncthreads();             // (5)
    STORE_WX(acc);
    __syncthreads();             // (6) Wx(h1,k0) visible

    // ===== seg 3: P2(h1,k0) || P1(h1,k1) =====
    ZERO_ACC(acc);
    SEG_FUSED(acc, Wk1, 1, 1, 0);
    __syncthreads();             // (7)
    STORE_WX(acc);
    __syncthreads();             // (8) Wx(h1,k1) visible

    // ===== tail: P2(h1,k1) =====
    P2_TILE(0, 1, 1);
    P2_TILE(1, 1, 1);
    P2_TILE(2, 1, 1);

    // ===== epilogue: tanh -> Ts (overlays Wxh), U-dot, fused softmax =====
    __syncthreads();             // (9)
    float* Ts = (float*)Wxh;     // padded addr = idx + (idx>>3)
    #pragma unroll
    for (int kk = 0; kk < 2; ++kk)
        #pragma unroll
        for (int it = 0; it < 3; ++it) {
            const int p = wave + it * 4;
            if (p < 9) {
                const int nt = p / 3, mt = p % 3;
                const int m = mt * 16 + l15;
                if (m < NF) {
                    #pragma unroll
                    for (int r = 0; r < 4; ++r) {
                        const int n = nt * 16 + quad * 4 + r;
                        if (n < NF) {
                            float x = sacc[kk][it][r] * C1F
                                      + v1s2[kk * 36 + n] + v2s2[kk * 36 + m];
                            float e = exp2f(x);
                            const int idx = kk * NN2 + n * NF + m;
                            Ts[idx + (idx >> 3)] = 1.f - 2.f / (e + 1.f);
                        }
                    }
                }
            }
        }
    __syncthreads();
    #pragma unroll
    for (int u0 = 0; u0 < 2; ++u0) {
        const int u = t + u0 * 256;
        if (u < 324) {
            const float* tp = Ts + u * 9;
            float lg = Uws[8];
            #pragma unroll
            for (int j = 0; j < 8; ++j) lg += Uws[j] * tp[j];
            Ls[u] = lg;
        }
    }
    __syncthreads();
    #pragma unroll
    for (int rr0 = 0; rr0 < 3; ++rr0) {
        const int rr = wave + rr0 * 4;
        if (rr < 9) {
            float v = (lane < NF) ? Ls[rr * 36 + lane] : -INFINITY;
            float mx = v;
            #pragma unroll
            for (int off = 32; off > 0; off >>= 1) mx = fmaxf(mx, __shfl_xor(mx, off));
            float e = (lane < NF) ? __expf(v - mx) : 0.f;
            float sm = e;
            #pragma unroll
            for (int off = 32; off > 0; off >>= 1) sm += __shfl_xor(sm, off);
            if (lane < NF)
                out[(size_t)b * NN2 + kp * 324 + rr * 36 + lane] = e / sm;
        }
    }
}

extern "C" void kernel_launch(void* const* d_in, const int* in_sizes, int n_in,
                              void* d_out, int out_size, void* d_ws, size_t ws_size,
                              hipStream_t stream) {
    const float* texts = (const float*)d_in[0];
    const float* W     = (const float*)d_in[1];
    const float* Wb    = (const float*)d_in[2];
    const float* V1w   = (const float*)d_in[3];
    const float* V1b   = (const float*)d_in[4];
    const float* V2w   = (const float*)d_in[5];
    const float* V2b   = (const float*)d_in[6];
    const float* Uw    = (const float*)d_in[7];
    const float* Ub    = (const float*)d_in[8];

    char* ws = (char*)d_ws;
    f16x8* WfH = (f16x8*)ws;                                   //  1 MiB
    float* outp = (float*)d_out;

    hipFuncSetAttribute((const void*)wpack,
                        hipFuncAttributeMaxDynamicSharedMemorySize, SMEM_PREP);
    hipFuncSetAttribute((const void*)ntn_main,
                        hipFuncAttributeMaxDynamicSharedMemorySize, SMEM_MAIN);

    wpack<<<128, 256, SMEM_PREP, stream>>>(W, WfH);
    ntn_main<<<NB * NK / 2, 256, SMEM_MAIN, stream>>>(texts, WfH,
                                                      V1w, V1b, V2w, V2b, Wb,
                                                      Uw, Ub, outp);
}